// Round 4
// baseline (1889.346 us; speedup 1.0000x reference)
//
#include <hip/hip_runtime.h>

#define T_TOKENS 16384
#define HDIM 1024
#define FDIM 4096
#define NEXP 8
#define TM 128
#define PAIR_MAX 33792   // 32768 pairs + 8*128 max padding
#define MAX_RT 264       // max row tiles: floor((32768-8)/128)+8 = 263

typedef _Float16 f16;
typedef _Float16 f16x8 __attribute__((ext_vector_type(8)));
typedef _Float16 f16x4 __attribute__((ext_vector_type(4)));
typedef float f32x4 __attribute__((ext_vector_type(4)));

__device__ __forceinline__ void gload_lds16(const void* g, void* l) {
    __builtin_amdgcn_global_load_lds(
        (const __attribute__((address_space(1))) unsigned int*)g,
        (__attribute__((address_space(3))) unsigned int*)l, 16, 0, 0);
}

// ---------------- transpose + fp16 cast: W[E][R][C] fp32 -> WT[E][C][R] fp16
__global__ void __launch_bounds__(256) transpose_kernel(
    const float* __restrict__ W, f16* __restrict__ WT, int R, int C)
{
    const int e = blockIdx.x;
    const int r0 = blockIdx.y * 32, c0 = blockIdx.z * 32;
    __shared__ float tile[32][33];
    const int tid = threadIdx.x;
    const int rr = tid >> 3, cc = (tid & 7) * 4;
    float4 v = *(const float4*)(W + ((size_t)e * R + r0 + rr) * C + c0 + cc);
    tile[rr][cc + 0] = v.x; tile[rr][cc + 1] = v.y;
    tile[rr][cc + 2] = v.z; tile[rr][cc + 3] = v.w;
    __syncthreads();
    f16x4 hv;
    hv[0] = (f16)tile[cc + 0][rr];
    hv[1] = (f16)tile[cc + 1][rr];
    hv[2] = (f16)tile[cc + 2][rr];
    hv[3] = (f16)tile[cc + 3][rr];
    *(f16x4*)(WT + ((size_t)e * C + c0 + rr) * R + r0 + cc) = hv;
}

// ---------------- fused LayerNorm + router (softmax over 8, top-2) ----------
__global__ void __launch_bounds__(256) router_kernel(
    const float* __restrict__ x, const float* __restrict__ gamma,
    const float* __restrict__ beta, const float* __restrict__ Wr,
    const float* __restrict__ br,
    f16* __restrict__ xnh, float* __restrict__ scores, int* __restrict__ sidx,
    float* __restrict__ ssum, int* __restrict__ counts)
{
    const int t = blockIdx.x;
    const int tid = threadIdx.x;
    const int lane = tid & 63, wid = tid >> 6;

    float4 v = ((const float4*)(x + (size_t)t * HDIM))[tid];
    float s = v.x + v.y + v.z + v.w;
    float q = v.x * v.x + v.y * v.y + v.z * v.z + v.w * v.w;
#pragma unroll
    for (int o = 32; o > 0; o >>= 1) { s += __shfl_down(s, o); q += __shfl_down(q, o); }

    __shared__ float red[8];
    __shared__ float stat[2];
    if (lane == 0) { red[wid] = s; red[4 + wid] = q; }
    __syncthreads();
    if (tid == 0) {
        float S = red[0] + red[1] + red[2] + red[3];
        float Q = red[4] + red[5] + red[6] + red[7];
        float mu = S * (1.0f / HDIM);
        float var = Q * (1.0f / HDIM) - mu * mu;
        stat[0] = mu; stat[1] = rsqrtf(var + 1e-5f);
    }
    __syncthreads();
    const float mu = stat[0], rstd = stat[1];
    float4 gv = ((const float4*)gamma)[tid];
    float4 bv = ((const float4*)beta)[tid];
    float xn[4];
    xn[0] = (v.x - mu) * rstd * gv.x + bv.x;
    xn[1] = (v.y - mu) * rstd * gv.y + bv.y;
    xn[2] = (v.z - mu) * rstd * gv.z + bv.z;
    xn[3] = (v.w - mu) * rstd * gv.w + bv.w;
    f16x4 hv;
    hv[0] = (f16)xn[0]; hv[1] = (f16)xn[1]; hv[2] = (f16)xn[2]; hv[3] = (f16)xn[3];
    *(f16x4*)(xnh + (size_t)t * HDIM + tid * 4) = hv;

    float lg[8] = {0, 0, 0, 0, 0, 0, 0, 0};
#pragma unroll
    for (int j = 0; j < 4; ++j) {
        const float4* wr = (const float4*)(Wr + (size_t)(tid * 4 + j) * NEXP);
        float4 w0 = wr[0], w1 = wr[1];
        lg[0] += xn[j] * w0.x; lg[1] += xn[j] * w0.y;
        lg[2] += xn[j] * w0.z; lg[3] += xn[j] * w0.w;
        lg[4] += xn[j] * w1.x; lg[5] += xn[j] * w1.y;
        lg[6] += xn[j] * w1.z; lg[7] += xn[j] * w1.w;
    }
#pragma unroll
    for (int o = 32; o > 0; o >>= 1) {
#pragma unroll
        for (int e = 0; e < 8; ++e) lg[e] += __shfl_down(lg[e], o);
    }
    __shared__ float lred[4][8];
    if (lane == 0) {
#pragma unroll
        for (int e = 0; e < 8; ++e) lred[wid][e] = lg[e];
    }
    __syncthreads();
    if (tid == 0) {
        float L[8], m = -1e30f;
        for (int e = 0; e < 8; ++e) {
            L[e] = lred[0][e] + lred[1][e] + lred[2][e] + lred[3][e] + br[e];
            m = fmaxf(m, L[e]);
        }
        float p[8], Z = 0.f;
        for (int e = 0; e < 8; ++e) { p[e] = expf(L[e] - m); Z += p[e]; }
        float invZ = 1.f / Z;
        float best = -1.f, sec = -1.f; int be = 0, se = 0;
        for (int e = 0; e < 8; ++e) {
            float pe = p[e] * invZ;
            if (pe > best) { sec = best; se = be; best = pe; be = e; }
            else if (pe > sec) { sec = pe; se = e; }
        }
        scores[t * 2] = best; scores[t * 2 + 1] = sec;
        sidx[t * 2] = be; sidx[t * 2 + 1] = se;
        ssum[t] = best + sec;
        atomicAdd(&counts[be], 1);
        atomicAdd(&counts[se], 1);
    }
}

// ---------------- expert segment offsets + tile table ------------------------
__global__ void offsets_kernel(const int* __restrict__ counts, int* __restrict__ bases,
                               int* __restrict__ cursor, int* __restrict__ tile_e,
                               int* __restrict__ tile_row0, int* __restrict__ ntiles)
{
    if (threadIdx.x == 0) {
        int cur = 0, rt = 0;
        for (int e = 0; e < NEXP; ++e) {
            bases[e] = cur; cursor[e] = 0;
            int c = counts[e];
            int nt = (c + TM - 1) / TM;
            for (int i = 0; i < nt; ++i) { tile_e[rt] = e; tile_row0[rt] = cur + i * TM; rt++; }
            cur += nt * TM;
        }
        *ntiles = rt;
    }
}

__global__ void __launch_bounds__(256) scatter_kernel(
    const int* __restrict__ sidx, const float* __restrict__ scores,
    const int* __restrict__ bases, int* __restrict__ cursor,
    int* __restrict__ pair_token, float* __restrict__ pair_score)
{
    int t = blockIdx.x * 256 + threadIdx.x;
#pragma unroll
    for (int k = 0; k < 2; ++k) {
        int e = sidx[t * 2 + k];
        int slot = atomicAdd(&cursor[e], 1);
        int p = bases[e] + slot;
        pair_token[p] = t;
        pair_score[p] = scores[t * 2 + k];
    }
}

// ---------------- c_total[h] = sum_e relu(b1_e)@W2_e + sum_e b2_e ------------
__global__ void __launch_bounds__(256) ctotal_kernel(
    const float* __restrict__ b1, const float* __restrict__ W2,
    const float* __restrict__ b2, float* __restrict__ c_total)
{
    const int e = blockIdx.x, ch = blockIdx.y;
    const int tid = threadIdx.x;
    const int h0 = tid * 4;
    float a0 = 0, a1 = 0, a2 = 0, a3 = 0;
    for (int f = ch * 256; f < ch * 256 + 256; ++f) {
        float a = fmaxf(b1[e * FDIM + f], 0.f);
        if (a != 0.f) {
            float4 w = *(const float4*)(W2 + ((size_t)e * FDIM + f) * HDIM + h0);
            a0 += a * w.x; a1 += a * w.y; a2 += a * w.z; a3 += a * w.w;
        }
    }
    if (ch == 0) {
        float4 b2v = *(const float4*)(b2 + e * HDIM + h0);
        a0 += b2v.x; a1 += b2v.y; a2 += b2v.z; a3 += b2v.w;
    }
    atomicAdd(&c_total[h0 + 0], a0);
    atomicAdd(&c_total[h0 + 1], a1);
    atomicAdd(&c_total[h0 + 2], a2);
    atomicAdd(&c_total[h0 + 3], a3);
}

// ---------------- out = x + ssum * c_total -----------------------------------
__global__ void __launch_bounds__(256) init_kernel(
    const float* __restrict__ x, const float* __restrict__ ssum,
    const float* __restrict__ c_total, float* __restrict__ out)
{
    const int t = blockIdx.x, tid = threadIdx.x;
    float sv = ssum[t];
    float4 xv = ((const float4*)(x + (size_t)t * HDIM))[tid];
    float4 cv = ((const float4*)c_total)[tid];
    float4 o = {xv.x + sv * cv.x, xv.y + sv * cv.y, xv.z + sv * cv.z, xv.w + sv * cv.w};
    ((float4*)(out + (size_t)t * HDIM))[tid] = o;
}

// ---------------- GEMM1: g = relu(xn@W1_e + b1_e) - relu(b1_e), fp16 out -----
// A: gathered xn rows [M x 1024], B: W1T[e] [F x 1024] (n-major, k-contig)
__global__ void __launch_bounds__(256, 2) gemm1_kernel(
    const f16* __restrict__ xnh, const f16* __restrict__ W1T,
    const float* __restrict__ b1, const int* __restrict__ pair_token,
    const int* __restrict__ tile_e, const int* __restrict__ tile_row0,
    const int* __restrict__ ntiles, f16* __restrict__ g)
{
    const int rt = blockIdx.x;
    if (rt >= *ntiles) return;
    const int e = tile_e[rt];
    const int row0 = tile_row0[rt];
    const int n0 = blockIdx.y * 128;
    const int tid = threadIdx.x;
    const int wave = tid >> 6, lane = tid & 63;
    const int l15 = lane & 15, lk = lane >> 4;
    const int wm = wave >> 1, wn = wave & 1;

    __shared__ __align__(16) f16 As[128 * 64];
    __shared__ __align__(16) f16 Bs[128 * 64];

    const f16* asrc[4];
#pragma unroll
    for (int it = 0; it < 4; ++it) {
        int i = it * 256 + tid;
        int tok = pair_token[row0 + (i >> 3)];
        if (tok < 0) tok = 0;  // padding row: load harmless valid data
        asrc[it] = xnh + (size_t)tok * HDIM + (i & 7) * 8;
    }
    const f16* bbase = W1T + ((size_t)e * FDIM + n0) * HDIM;

    f32x4 acc[4][4];
    const f32x4 vzero = {0.f, 0.f, 0.f, 0.f};
#pragma unroll
    for (int a0 = 0; a0 < 4; ++a0)
#pragma unroll
        for (int b0 = 0; b0 < 4; ++b0) acc[a0][b0] = vzero;

    for (int k0 = 0; k0 < HDIM; k0 += 64) {
#pragma unroll
        for (int it = 0; it < 4; ++it) {
            int i = it * 256 + tid;
            gload_lds16(asrc[it] + k0, &As[(size_t)(i & ~63) * 8]);
            gload_lds16(bbase + (size_t)(i >> 3) * HDIM + (i & 7) * 8 + k0,
                        &Bs[(size_t)(i & ~63) * 8]);
        }
        __syncthreads();
#pragma unroll
        for (int ks = 0; ks < 64; ks += 32) {
            f16x8 af[4], bf[4];
#pragma unroll
            for (int fm = 0; fm < 4; ++fm)
                af[fm] = *(const f16x8*)&As[(wm * 64 + fm * 16 + l15) * 64 + ks + lk * 8];
#pragma unroll
            for (int fn = 0; fn < 4; ++fn)
                bf[fn] = *(const f16x8*)&Bs[(wn * 64 + fn * 16 + l15) * 64 + ks + lk * 8];
#pragma unroll
            for (int fm = 0; fm < 4; ++fm)
#pragma unroll
                for (int fn = 0; fn < 4; ++fn)
                    acc[fm][fn] = __builtin_amdgcn_mfma_f32_16x16x32_f16(
                        af[fm], bf[fn], acc[fm][fn], 0, 0, 0);
        }
        __syncthreads();
    }

#pragma unroll
    for (int fn = 0; fn < 4; ++fn) {
        int n = n0 + wn * 64 + fn * 16 + l15;
        float b1v = b1[e * FDIM + n];
        float rb = fmaxf(b1v, 0.f);
#pragma unroll
        for (int fm = 0; fm < 4; ++fm) {
#pragma unroll
            for (int r = 0; r < 4; ++r) {
                int mrow = wm * 64 + fm * 16 + lk * 4 + r;
                float z = acc[fm][fn][r] + b1v;
                g[(size_t)(row0 + mrow) * FDIM + n] = (f16)(fmaxf(z, 0.f) - rb);
            }
        }
    }
}

// ---------------- GEMM2: out[tok] += score * (g @ W2_e) ----------------------
// A: g rows [M x 4096], B: W2T[e] [H x 4096] (n-major, k-contig)
__global__ void __launch_bounds__(256, 2) gemm2_kernel(
    const f16* __restrict__ g, const f16* __restrict__ W2T,
    const int* __restrict__ pair_token, const float* __restrict__ pair_score,
    const int* __restrict__ tile_e, const int* __restrict__ tile_row0,
    const int* __restrict__ ntiles, float* __restrict__ out)
{
    const int rt = blockIdx.x;
    if (rt >= *ntiles) return;
    const int e = tile_e[rt];
    const int row0 = tile_row0[rt];
    const int n0 = blockIdx.y * 128;
    const int tid = threadIdx.x;
    const int wave = tid >> 6, lane = tid & 63;
    const int l15 = lane & 15, lk = lane >> 4;
    const int wm = wave >> 1, wn = wave & 1;

    __shared__ __align__(16) f16 As[128 * 64];
    __shared__ __align__(16) f16 Bs[128 * 64];

    const f16* bbase = W2T + ((size_t)e * HDIM + n0) * FDIM;

    f32x4 acc[4][4];
    const f32x4 vzero = {0.f, 0.f, 0.f, 0.f};
#pragma unroll
    for (int a0 = 0; a0 < 4; ++a0)
#pragma unroll
        for (int b0 = 0; b0 < 4; ++b0) acc[a0][b0] = vzero;

    for (int k0 = 0; k0 < FDIM; k0 += 64) {
#pragma unroll
        for (int it = 0; it < 4; ++it) {
            int i = it * 256 + tid;
            gload_lds16(g + (size_t)(row0 + (i >> 3)) * FDIM + (i & 7) * 8 + k0,
                        &As[(size_t)(i & ~63) * 8]);
            gload_lds16(bbase + (size_t)(i >> 3) * FDIM + (i & 7) * 8 + k0,
                        &Bs[(size_t)(i & ~63) * 8]);
        }
        __syncthreads();
#pragma unroll
        for (int ks = 0; ks < 64; ks += 32) {
            f16x8 af[4], bf[4];
#pragma unroll
            for (int fm = 0; fm < 4; ++fm)
                af[fm] = *(const f16x8*)&As[(wm * 64 + fm * 16 + l15) * 64 + ks + lk * 8];
#pragma unroll
            for (int fn = 0; fn < 4; ++fn)
                bf[fn] = *(const f16x8*)&Bs[(wn * 64 + fn * 16 + l15) * 64 + ks + lk * 8];
#pragma unroll
            for (int fm = 0; fm < 4; ++fm)
#pragma unroll
                for (int fn = 0; fn < 4; ++fn)
                    acc[fm][fn] = __builtin_amdgcn_mfma_f32_16x16x32_f16(
                        af[fm], bf[fn], acc[fm][fn], 0, 0, 0);
        }
        __syncthreads();
    }

#pragma unroll
    for (int fn = 0; fn < 4; ++fn) {
        int n = n0 + wn * 64 + fn * 16 + l15;
#pragma unroll
        for (int fm = 0; fm < 4; ++fm) {
#pragma unroll
            for (int r = 0; r < 4; ++r) {
                int prow = row0 + wm * 64 + fm * 16 + lk * 4 + r;
                int tok = pair_token[prow];
                if (tok >= 0) {
                    float sc = pair_score[prow];
                    atomicAdd(out + (size_t)tok * HDIM + n, sc * acc[fm][fn][r]);
                }
            }
        }
    }
}

extern "C" void kernel_launch(void* const* d_in, const int* in_sizes, int n_in,
                              void* d_out, int out_size, void* d_ws, size_t ws_size,
                              hipStream_t stream)
{
    const float* x     = (const float*)d_in[0];
    const float* gamma = (const float*)d_in[1];
    const float* beta  = (const float*)d_in[2];
    const float* Wr    = (const float*)d_in[3];
    const float* br    = (const float*)d_in[4];
    const float* W1    = (const float*)d_in[5];
    const float* b1    = (const float*)d_in[6];
    const float* W2    = (const float*)d_in[7];
    const float* b2    = (const float*)d_in[8];
    float* out = (float*)d_out;
    (void)in_sizes; (void)n_in; (void)out_size; (void)ws_size;

    char* ws = (char*)d_ws;
    size_t off = 0;
    auto carve = [&](size_t bytes) {
        char* p = ws + off;
        off += (bytes + 255) & ~(size_t)255;
        return p;
    };
    f16*   xnh        = (f16*)carve((size_t)T_TOKENS * HDIM * 2);        // 32 MiB
    f16*   w1t        = (f16*)carve((size_t)NEXP * FDIM * HDIM * 2);     // 64 MiB
    f16*   w2t        = (f16*)carve((size_t)NEXP * HDIM * FDIM * 2);     // 64 MiB
    f16*   gbuf       = (f16*)carve((size_t)PAIR_MAX * FDIM * 2);        // 264 MiB
    int*   pair_token = (int*)carve((size_t)PAIR_MAX * 4);
    float* pair_score = (float*)carve((size_t)PAIR_MAX * 4);
    float* scores     = (float*)carve((size_t)T_TOKENS * 2 * 4);
    int*   sidx       = (int*)carve((size_t)T_TOKENS * 2 * 4);
    float* ssum       = (float*)carve((size_t)T_TOKENS * 4);
    float* c_total    = (float*)carve((size_t)HDIM * 4);
    int*   counts     = (int*)carve(NEXP * 4);
    int*   cursor     = (int*)carve(NEXP * 4);
    int*   bases      = (int*)carve(NEXP * 4);
    int*   ntiles     = (int*)carve(4);
    int*   tile_e     = (int*)carve(MAX_RT * 4);
    int*   tile_row0  = (int*)carve(MAX_RT * 4);

    hipMemsetAsync(counts, 0, NEXP * 4, stream);
    hipMemsetAsync(c_total, 0, HDIM * 4, stream);
    hipMemsetAsync(pair_token, 0xFF, (size_t)PAIR_MAX * 4, stream);  // -1 = padding

    transpose_kernel<<<dim3(NEXP, HDIM / 32, FDIM / 32), 256, 0, stream>>>(W1, w1t, HDIM, FDIM);
    transpose_kernel<<<dim3(NEXP, FDIM / 32, HDIM / 32), 256, 0, stream>>>(W2, w2t, FDIM, HDIM);
    router_kernel<<<T_TOKENS, 256, 0, stream>>>(x, gamma, beta, Wr, br, xnh, scores, sidx, ssum, counts);
    offsets_kernel<<<1, 64, 0, stream>>>(counts, bases, cursor, tile_e, tile_row0, ntiles);
    scatter_kernel<<<T_TOKENS / 256, 256, 0, stream>>>(sidx, scores, bases, cursor, pair_token, pair_score);
    ctotal_kernel<<<dim3(NEXP, FDIM / 256), 256, 0, stream>>>(b1, W2, b2, c_total);
    init_kernel<<<T_TOKENS, 256, 0, stream>>>(x, ssum, c_total, out);
    gemm1_kernel<<<dim3(MAX_RT, FDIM / 128), 256, 0, stream>>>(
        xnh, w1t, b1, pair_token, tile_e, tile_row0, ntiles, gbuf);
    gemm2_kernel<<<dim3(MAX_RT, HDIM / 128), 256, 0, stream>>>(
        gbuf, w2t, pair_token, pair_score, tile_e, tile_row0, ntiles, out);
}

// Round 5
// 1684.120 us; speedup vs baseline: 1.1219x; 1.1219x over previous
//
#include <hip/hip_runtime.h>

#define T_TOKENS 16384
#define HDIM 1024
#define FDIM 4096
#define NEXP 8
#define TM 128
#define PAIR_MAX 33792   // 32768 pairs + 8*128 max padding
#define MAX_RT 264       // max row tiles: floor((32768-8)/128)+8 = 263

typedef _Float16 f16;
typedef _Float16 f16x8 __attribute__((ext_vector_type(8)));
typedef _Float16 f16x4 __attribute__((ext_vector_type(4)));
typedef float f32x4 __attribute__((ext_vector_type(4)));

__device__ __forceinline__ void gload_lds16(const void* g, void* l) {
    __builtin_amdgcn_global_load_lds(
        (const __attribute__((address_space(1))) unsigned int*)g,
        (__attribute__((address_space(3))) unsigned int*)l, 16, 0, 0);
}

// ---------------- transpose + fp16 cast: W[E][R][C] fp32 -> WT[E][C][R] fp16
__global__ void __launch_bounds__(256) transpose_kernel(
    const float* __restrict__ W, f16* __restrict__ WT, int R, int C)
{
    const int e = blockIdx.x;
    const int r0 = blockIdx.y * 32, c0 = blockIdx.z * 32;
    __shared__ float tile[32][33];
    const int tid = threadIdx.x;
    const int rr = tid >> 3, cc = (tid & 7) * 4;
    float4 v = *(const float4*)(W + ((size_t)e * R + r0 + rr) * C + c0 + cc);
    tile[rr][cc + 0] = v.x; tile[rr][cc + 1] = v.y;
    tile[rr][cc + 2] = v.z; tile[rr][cc + 3] = v.w;
    __syncthreads();
    f16x4 hv;
    hv[0] = (f16)tile[cc + 0][rr];
    hv[1] = (f16)tile[cc + 1][rr];
    hv[2] = (f16)tile[cc + 2][rr];
    hv[3] = (f16)tile[cc + 3][rr];
    *(f16x4*)(WT + ((size_t)e * C + c0 + rr) * R + r0 + cc) = hv;
}

// ---------------- fused LayerNorm + router (softmax over 8, top-2) ----------
__global__ void __launch_bounds__(256) router_kernel(
    const float* __restrict__ x, const float* __restrict__ gamma,
    const float* __restrict__ beta, const float* __restrict__ Wr,
    const float* __restrict__ br,
    f16* __restrict__ xnh, float* __restrict__ scores, int* __restrict__ sidx,
    float* __restrict__ ssum, int* __restrict__ counts)
{
    const int t = blockIdx.x;
    const int tid = threadIdx.x;
    const int lane = tid & 63, wid = tid >> 6;

    float4 v = ((const float4*)(x + (size_t)t * HDIM))[tid];
    float s = v.x + v.y + v.z + v.w;
    float q = v.x * v.x + v.y * v.y + v.z * v.z + v.w * v.w;
#pragma unroll
    for (int o = 32; o > 0; o >>= 1) { s += __shfl_down(s, o); q += __shfl_down(q, o); }

    __shared__ float red[8];
    __shared__ float stat[2];
    if (lane == 0) { red[wid] = s; red[4 + wid] = q; }
    __syncthreads();
    if (tid == 0) {
        float S = red[0] + red[1] + red[2] + red[3];
        float Q = red[4] + red[5] + red[6] + red[7];
        float mu = S * (1.0f / HDIM);
        float var = Q * (1.0f / HDIM) - mu * mu;
        stat[0] = mu; stat[1] = rsqrtf(var + 1e-5f);
    }
    __syncthreads();
    const float mu = stat[0], rstd = stat[1];
    float4 gv = ((const float4*)gamma)[tid];
    float4 bv = ((const float4*)beta)[tid];
    float xn[4];
    xn[0] = (v.x - mu) * rstd * gv.x + bv.x;
    xn[1] = (v.y - mu) * rstd * gv.y + bv.y;
    xn[2] = (v.z - mu) * rstd * gv.z + bv.z;
    xn[3] = (v.w - mu) * rstd * gv.w + bv.w;
    f16x4 hv;
    hv[0] = (f16)xn[0]; hv[1] = (f16)xn[1]; hv[2] = (f16)xn[2]; hv[3] = (f16)xn[3];
    *(f16x4*)(xnh + (size_t)t * HDIM + tid * 4) = hv;

    float lg[8] = {0, 0, 0, 0, 0, 0, 0, 0};
#pragma unroll
    for (int j = 0; j < 4; ++j) {
        const float4* wr = (const float4*)(Wr + (size_t)(tid * 4 + j) * NEXP);
        float4 w0 = wr[0], w1 = wr[1];
        lg[0] += xn[j] * w0.x; lg[1] += xn[j] * w0.y;
        lg[2] += xn[j] * w0.z; lg[3] += xn[j] * w0.w;
        lg[4] += xn[j] * w1.x; lg[5] += xn[j] * w1.y;
        lg[6] += xn[j] * w1.z; lg[7] += xn[j] * w1.w;
    }
#pragma unroll
    for (int o = 32; o > 0; o >>= 1) {
#pragma unroll
        for (int e = 0; e < 8; ++e) lg[e] += __shfl_down(lg[e], o);
    }
    __shared__ float lred[4][8];
    if (lane == 0) {
#pragma unroll
        for (int e = 0; e < 8; ++e) lred[wid][e] = lg[e];
    }
    __syncthreads();
    if (tid == 0) {
        float L[8], m = -1e30f;
        for (int e = 0; e < 8; ++e) {
            L[e] = lred[0][e] + lred[1][e] + lred[2][e] + lred[3][e] + br[e];
            m = fmaxf(m, L[e]);
        }
        float p[8], Z = 0.f;
        for (int e = 0; e < 8; ++e) { p[e] = expf(L[e] - m); Z += p[e]; }
        float invZ = 1.f / Z;
        float best = -1.f, sec = -1.f; int be = 0, se = 0;
        for (int e = 0; e < 8; ++e) {
            float pe = p[e] * invZ;
            if (pe > best) { sec = best; se = be; best = pe; be = e; }
            else if (pe > sec) { sec = pe; se = e; }
        }
        scores[t * 2] = best; scores[t * 2 + 1] = sec;
        sidx[t * 2] = be; sidx[t * 2 + 1] = se;
        ssum[t] = best + sec;
        atomicAdd(&counts[be], 1);
        atomicAdd(&counts[se], 1);
    }
}

// ---------------- expert segment offsets + tile table ------------------------
__global__ void offsets_kernel(const int* __restrict__ counts, int* __restrict__ bases,
                               int* __restrict__ cursor, int* __restrict__ tile_e,
                               int* __restrict__ tile_row0, int* __restrict__ ntiles)
{
    if (threadIdx.x == 0) {
        int cur = 0, rt = 0;
        for (int e = 0; e < NEXP; ++e) {
            bases[e] = cur; cursor[e] = 0;
            int c = counts[e];
            int nt = (c + TM - 1) / TM;
            for (int i = 0; i < nt; ++i) { tile_e[rt] = e; tile_row0[rt] = cur + i * TM; rt++; }
            cur += nt * TM;
        }
        *ntiles = rt;
    }
}

__global__ void __launch_bounds__(256) scatter_kernel(
    const int* __restrict__ sidx, const float* __restrict__ scores,
    const int* __restrict__ bases, int* __restrict__ cursor,
    int* __restrict__ pair_token, float* __restrict__ pair_score)
{
    int t = blockIdx.x * 256 + threadIdx.x;
#pragma unroll
    for (int k = 0; k < 2; ++k) {
        int e = sidx[t * 2 + k];
        int slot = atomicAdd(&cursor[e], 1);
        int p = bases[e] + slot;
        pair_token[p] = t;
        pair_score[p] = scores[t * 2 + k];
    }
}

// ---------------- c_total[h] = sum_e relu(b1_e)@W2_e + sum_e b2_e ------------
__global__ void __launch_bounds__(256) ctotal_kernel(
    const float* __restrict__ b1, const float* __restrict__ W2,
    const float* __restrict__ b2, float* __restrict__ c_total)
{
    const int e = blockIdx.x, ch = blockIdx.y;
    const int tid = threadIdx.x;
    const int h0 = tid * 4;
    float a0 = 0, a1 = 0, a2 = 0, a3 = 0;
    for (int f = ch * 256; f < ch * 256 + 256; ++f) {
        float a = fmaxf(b1[e * FDIM + f], 0.f);
        if (a != 0.f) {
            float4 w = *(const float4*)(W2 + ((size_t)e * FDIM + f) * HDIM + h0);
            a0 += a * w.x; a1 += a * w.y; a2 += a * w.z; a3 += a * w.w;
        }
    }
    if (ch == 0) {
        float4 b2v = *(const float4*)(b2 + e * HDIM + h0);
        a0 += b2v.x; a1 += b2v.y; a2 += b2v.z; a3 += b2v.w;
    }
    atomicAdd(&c_total[h0 + 0], a0);
    atomicAdd(&c_total[h0 + 1], a1);
    atomicAdd(&c_total[h0 + 2], a2);
    atomicAdd(&c_total[h0 + 3], a3);
}

// ---------------- out = x + ssum * c_total -----------------------------------
__global__ void __launch_bounds__(256) init_kernel(
    const float* __restrict__ x, const float* __restrict__ ssum,
    const float* __restrict__ c_total, float* __restrict__ out)
{
    const int t = blockIdx.x, tid = threadIdx.x;
    float sv = ssum[t];
    float4 xv = ((const float4*)(x + (size_t)t * HDIM))[tid];
    float4 cv = ((const float4*)c_total)[tid];
    float4 o = {xv.x + sv * cv.x, xv.y + sv * cv.y, xv.z + sv * cv.z, xv.w + sv * cv.w};
    ((float4*)(out + (size_t)t * HDIM))[tid] = o;
}

// ===== GEMM tiles: T2 XOR swizzle =====
// LDS row r (128B), slot s (16B) holds global slot s^(r&7): write-side via
// inverse-swizzled per-lane global SOURCE (gload_lds dest stays linear,
// rule #21), read-side via XOR on the ds_read element offset.
// Removes the 16-way same-bank conflict (rows are 128B apart -> bank 0 for
// all 16 lanes of a fragment column). Measured 1.02e8 conflict-cycles ~= 29%
// of CU time in r4.

// ---------------- GEMM1: g = relu(xn@W1_e + b1_e) - relu(b1_e), fp16 out -----
// Grid: 1-D, n0-fastest (idx%32) so consecutive blocks (round-robin XCDs)
// share one A-tile via L3; each XCD's L2 keeps 4 B-panels/expert resident.
__global__ void __launch_bounds__(256, 2) gemm1_kernel(
    const f16* __restrict__ xnh, const f16* __restrict__ W1T,
    const float* __restrict__ b1, const int* __restrict__ pair_token,
    const int* __restrict__ tile_e, const int* __restrict__ tile_row0,
    const int* __restrict__ ntiles, f16* __restrict__ g)
{
    const int idx = blockIdx.x;
    const int rt = idx >> 5;               // 32 n-tiles (FDIM/128)
    if (rt >= *ntiles) return;
    const int n0 = (idx & 31) * 128;
    const int e = tile_e[rt];
    const int row0 = tile_row0[rt];
    const int tid = threadIdx.x;
    const int wave = tid >> 6, lane = tid & 63;
    const int l15 = lane & 15, lk = lane >> 4;
    const int wm = wave >> 1, wn = wave & 1;
    const int sx = l15 & 7;                // read-side swizzle key (= row&7)

    __shared__ __align__(16) f16 As[128 * 64];
    __shared__ __align__(16) f16 Bs[128 * 64];

    const f16* asrc[4];
    int bso[4];
#pragma unroll
    for (int it = 0; it < 4; ++it) {
        int i = it * 256 + tid;
        int so = (((i & 7) ^ ((i >> 3) & 7)) << 3);  // swizzled source slot
        int tok = pair_token[row0 + (i >> 3)];
        if (tok < 0) tok = 0;  // padding row: load harmless valid data
        asrc[it] = xnh + (size_t)tok * HDIM + so;
        bso[it] = so;
    }
    const f16* bbase = W1T + ((size_t)e * FDIM + n0) * HDIM;

    f32x4 acc[4][4];
    const f32x4 vzero = {0.f, 0.f, 0.f, 0.f};
#pragma unroll
    for (int a0 = 0; a0 < 4; ++a0)
#pragma unroll
        for (int b0 = 0; b0 < 4; ++b0) acc[a0][b0] = vzero;

    for (int k0 = 0; k0 < HDIM; k0 += 64) {
#pragma unroll
        for (int it = 0; it < 4; ++it) {
            int i = it * 256 + tid;
            gload_lds16(asrc[it] + k0, &As[(size_t)(i & ~63) * 8]);
            gload_lds16(bbase + (size_t)(i >> 3) * HDIM + bso[it] + k0,
                        &Bs[(size_t)(i & ~63) * 8]);
        }
        __syncthreads();
#pragma unroll
        for (int ks = 0; ks < 64; ks += 32) {
            const int soff = (((lk + (ks >> 3)) ^ sx) << 3);
            f16x8 af[4], bf[4];
#pragma unroll
            for (int fm = 0; fm < 4; ++fm)
                af[fm] = *(const f16x8*)&As[(wm * 64 + fm * 16 + l15) * 64 + soff];
#pragma unroll
            for (int fn = 0; fn < 4; ++fn)
                bf[fn] = *(const f16x8*)&Bs[(wn * 64 + fn * 16 + l15) * 64 + soff];
#pragma unroll
            for (int fm = 0; fm < 4; ++fm)
#pragma unroll
                for (int fn = 0; fn < 4; ++fn)
                    acc[fm][fn] = __builtin_amdgcn_mfma_f32_16x16x32_f16(
                        af[fm], bf[fn], acc[fm][fn], 0, 0, 0);
        }
        __syncthreads();
    }

#pragma unroll
    for (int fn = 0; fn < 4; ++fn) {
        int n = n0 + wn * 64 + fn * 16 + l15;
        float b1v = b1[e * FDIM + n];
        float rb = fmaxf(b1v, 0.f);
#pragma unroll
        for (int fm = 0; fm < 4; ++fm) {
#pragma unroll
            for (int r = 0; r < 4; ++r) {
                int mrow = wm * 64 + fm * 16 + lk * 4 + r;
                float z = acc[fm][fn][r] + b1v;
                g[(size_t)(row0 + mrow) * FDIM + n] = (f16)(fmaxf(z, 0.f) - rb);
            }
        }
    }
}

// ---------------- GEMM2: out[tok] += score * (g @ W2_e) ----------------------
// Grid: 1-D, n0-fastest (idx%8): each XCD pins ONE n0 panel (1 MB/expert in
// its L2); the 8 co-scheduled blocks of one rt share the A-tile via L3.
__global__ void __launch_bounds__(256, 2) gemm2_kernel(
    const f16* __restrict__ g, const f16* __restrict__ W2T,
    const int* __restrict__ pair_token, const float* __restrict__ pair_score,
    const int* __restrict__ tile_e, const int* __restrict__ tile_row0,
    const int* __restrict__ ntiles, float* __restrict__ out)
{
    const int idx = blockIdx.x;
    const int rt = idx >> 3;               // 8 n-tiles (HDIM/128)
    if (rt >= *ntiles) return;
    const int n0 = (idx & 7) * 128;
    const int e = tile_e[rt];
    const int row0 = tile_row0[rt];
    const int tid = threadIdx.x;
    const int wave = tid >> 6, lane = tid & 63;
    const int l15 = lane & 15, lk = lane >> 4;
    const int wm = wave >> 1, wn = wave & 1;
    const int sx = l15 & 7;

    __shared__ __align__(16) f16 As[128 * 64];
    __shared__ __align__(16) f16 Bs[128 * 64];

    const f16* bbase = W2T + ((size_t)e * HDIM + n0) * FDIM;

    f32x4 acc[4][4];
    const f32x4 vzero = {0.f, 0.f, 0.f, 0.f};
#pragma unroll
    for (int a0 = 0; a0 < 4; ++a0)
#pragma unroll
        for (int b0 = 0; b0 < 4; ++b0) acc[a0][b0] = vzero;

    for (int k0 = 0; k0 < FDIM; k0 += 64) {
#pragma unroll
        for (int it = 0; it < 4; ++it) {
            int i = it * 256 + tid;
            int so = (((i & 7) ^ ((i >> 3) & 7)) << 3);
            gload_lds16(g + (size_t)(row0 + (i >> 3)) * FDIM + so + k0,
                        &As[(size_t)(i & ~63) * 8]);
            gload_lds16(bbase + (size_t)(i >> 3) * FDIM + so + k0,
                        &Bs[(size_t)(i & ~63) * 8]);
        }
        __syncthreads();
#pragma unroll
        for (int ks = 0; ks < 64; ks += 32) {
            const int soff = (((lk + (ks >> 3)) ^ sx) << 3);
            f16x8 af[4], bf[4];
#pragma unroll
            for (int fm = 0; fm < 4; ++fm)
                af[fm] = *(const f16x8*)&As[(wm * 64 + fm * 16 + l15) * 64 + soff];
#pragma unroll
            for (int fn = 0; fn < 4; ++fn)
                bf[fn] = *(const f16x8*)&Bs[(wn * 64 + fn * 16 + l15) * 64 + soff];
#pragma unroll
            for (int fm = 0; fm < 4; ++fm)
#pragma unroll
                for (int fn = 0; fn < 4; ++fn)
                    acc[fm][fn] = __builtin_amdgcn_mfma_f32_16x16x32_f16(
                        af[fm], bf[fn], acc[fm][fn], 0, 0, 0);
        }
        __syncthreads();
    }

#pragma unroll
    for (int fn = 0; fn < 4; ++fn) {
        int n = n0 + wn * 64 + fn * 16 + l15;
#pragma unroll
        for (int fm = 0; fm < 4; ++fm) {
#pragma unroll
            for (int r = 0; r < 4; ++r) {
                int prow = row0 + wm * 64 + fm * 16 + lk * 4 + r;
                int tok = pair_token[prow];
                if (tok >= 0) {
                    float sc = pair_score[prow];
                    atomicAdd(out + (size_t)tok * HDIM + n, sc * acc[fm][fn][r]);
                }
            }
        }
    }
}

extern "C" void kernel_launch(void* const* d_in, const int* in_sizes, int n_in,
                              void* d_out, int out_size, void* d_ws, size_t ws_size,
                              hipStream_t stream)
{
    const float* x     = (const float*)d_in[0];
    const float* gamma = (const float*)d_in[1];
    const float* beta  = (const float*)d_in[2];
    const float* Wr    = (const float*)d_in[3];
    const float* br    = (const float*)d_in[4];
    const float* W1    = (const float*)d_in[5];
    const float* b1    = (const float*)d_in[6];
    const float* W2    = (const float*)d_in[7];
    const float* b2    = (const float*)d_in[8];
    float* out = (float*)d_out;
    (void)in_sizes; (void)n_in; (void)out_size; (void)ws_size;

    char* ws = (char*)d_ws;
    size_t off = 0;
    auto carve = [&](size_t bytes) {
        char* p = ws + off;
        off += (bytes + 255) & ~(size_t)255;
        return p;
    };
    f16*   xnh        = (f16*)carve((size_t)T_TOKENS * HDIM * 2);        // 32 MiB
    f16*   w1t        = (f16*)carve((size_t)NEXP * FDIM * HDIM * 2);     // 64 MiB
    f16*   w2t        = (f16*)carve((size_t)NEXP * HDIM * FDIM * 2);     // 64 MiB
    f16*   gbuf       = (f16*)carve((size_t)PAIR_MAX * FDIM * 2);        // 264 MiB
    int*   pair_token = (int*)carve((size_t)PAIR_MAX * 4);
    float* pair_score = (float*)carve((size_t)PAIR_MAX * 4);
    float* scores     = (float*)carve((size_t)T_TOKENS * 2 * 4);
    int*   sidx       = (int*)carve((size_t)T_TOKENS * 2 * 4);
    float* ssum       = (float*)carve((size_t)T_TOKENS * 4);
    float* c_total    = (float*)carve((size_t)HDIM * 4);
    int*   counts     = (int*)carve(NEXP * 4);
    int*   cursor     = (int*)carve(NEXP * 4);
    int*   bases      = (int*)carve(NEXP * 4);
    int*   ntiles     = (int*)carve(4);
    int*   tile_e     = (int*)carve(MAX_RT * 4);
    int*   tile_row0  = (int*)carve(MAX_RT * 4);

    hipMemsetAsync(counts, 0, NEXP * 4, stream);
    hipMemsetAsync(c_total, 0, HDIM * 4, stream);
    hipMemsetAsync(pair_token, 0xFF, (size_t)PAIR_MAX * 4, stream);  // -1 = padding

    transpose_kernel<<<dim3(NEXP, HDIM / 32, FDIM / 32), 256, 0, stream>>>(W1, w1t, HDIM, FDIM);
    transpose_kernel<<<dim3(NEXP, FDIM / 32, HDIM / 32), 256, 0, stream>>>(W2, w2t, FDIM, HDIM);
    router_kernel<<<T_TOKENS, 256, 0, stream>>>(x, gamma, beta, Wr, br, xnh, scores, sidx, ssum, counts);
    offsets_kernel<<<1, 64, 0, stream>>>(counts, bases, cursor, tile_e, tile_row0, ntiles);
    scatter_kernel<<<T_TOKENS / 256, 256, 0, stream>>>(sidx, scores, bases, cursor, pair_token, pair_score);
    ctotal_kernel<<<dim3(NEXP, FDIM / 256), 256, 0, stream>>>(b1, W2, b2, c_total);
    init_kernel<<<T_TOKENS, 256, 0, stream>>>(x, ssum, c_total, out);
    gemm1_kernel<<<MAX_RT * 32, 256, 0, stream>>>(
        xnh, w1t, b1, pair_token, tile_e, tile_row0, ntiles, gbuf);
    gemm2_kernel<<<MAX_RT * 8, 256, 0, stream>>>(
        gbuf, w2t, pair_token, pair_score, tile_e, tile_row0, ntiles, out);
}